// Round 9
// baseline (3346.710 us; speedup 1.0000x reference)
//
#include <hip/hip_runtime.h>
#include <hip/hip_bf16.h>
#include <cstdint>
#include <cstddef>

// ---------------------------------------------------------------------------
// DisentangledMultiHeadAttention: B=8, H=2, T=2048, D=2048, C=4096
// 256x256-tile bf16 MFMA GEMM, **4 waves x 128x128 output each** (dupA=dupB=2
// -> LDS fragment traffic 64KB/slab vs 96KB for 8-wave 2Mx4N; measured regime
// is read+MFMA SERIALIZED, so cutting LDS bytes cuts slab time directly).
// K-slab ring (4 x K=32, 128KB LDS), single barrier per slab, counted vmcnt:
//   phase p: vmcnt(16) [slab p landed; 2 slabs in flight behind]; s_barrier;
//            STAGE(p+3) [8 gld_lds/thread-wave]; 16x ds_read_b128;
//            setprio1; 64x mfma 16x16x32; setprio0.
// WAR: slot (p-1)&3 reads are lgkm-drained before their MFMAs complete
// (compiler waitcnt) -> before that wave reaches barrier(p); STAGE(p+3)
// issues after barrier(p). RAW: vmcnt before barrier. (Proof validated by
// R8 passing with identical choreography.)
// acc 8x8xf32x4 = 256 regs -> __launch_bounds__(256,1), 1 wave/SIMD.
// LDS FRAGMENT-MAJOR 1KB units (0 bank conflicts both sides, measured).
// NT loads on dead fp32 inputs; NT stores on all streaming outputs.
// v stored TRANSPOSED so PV is NT; softmax emits bf16 probs for PV.
// ---------------------------------------------------------------------------

typedef short short8_t __attribute__((ext_vector_type(8)));
typedef float f32x4   __attribute__((ext_vector_type(4)));

__device__ __forceinline__ short f2bf(float f) {
  unsigned u = __builtin_bit_cast(unsigned, f);
  u = (u + 0x7FFFu + ((u >> 16) & 1u)) >> 16;   // round-to-nearest-even
  return (short)u;
}

__device__ __forceinline__ short8_t cvt8(f32x4 a, f32x4 b) {
  short8_t r;
  r[0] = f2bf(a[0]); r[1] = f2bf(a[1]); r[2] = f2bf(a[2]); r[3] = f2bf(a[3]);
  r[4] = f2bf(b[0]); r[5] = f2bf(b[1]); r[6] = f2bf(b[2]); r[7] = f2bf(b[3]);
  return r;
}

__device__ __forceinline__ void gld_lds16(const void* g, void* l) {
  __builtin_amdgcn_global_load_lds(
      (const __attribute__((address_space(1))) void*)g,
      (__attribute__((address_space(3))) void*)l, 16, 0, 0);
}

// fp32 -> bf16 bulk convert; NT loads (fp32 source is dead after this)
__global__ __launch_bounds__(256)
void cvt_f32_bf16(const float* __restrict__ src, short* __restrict__ dst, int n8) {
  for (int i = blockIdx.x * blockDim.x + threadIdx.x; i < n8;
       i += gridDim.x * blockDim.x) {
    const f32x4* p = (const f32x4*)(src + (size_t)i * 8);
    f32x4 a = __builtin_nontemporal_load(p);
    f32x4 b = __builtin_nontemporal_load(p + 1);
    *(short8_t*)(dst + (size_t)i * 8) = cvt8(a, b);
  }
}

// MODE 0: q/k proj  C=bf16 (b,h,t,d)                 K=4096
// MODE 2: v proj    C=bf16 (b,h,d,s) [transposed]    K=4096
// MODE 3: scores    C=f32 scale+bias -> attn (d_out) K=2048, batched z
// MODE 4: PV        C=bf16 (b*T+t, h*D+d)            K=2048, batched z
// MODE 5: out proj  C=f32 y (d_out)                  K=4096
template<int MODE>
__global__ __launch_bounds__(256, 1)
void gemm256(const short* __restrict__ Ag, const short* __restrict__ Bg,
             void* __restrict__ Cg, const float* __restrict__ bias) {
  constexpr int K  = (MODE == 3 || MODE == 4) ? 2048 : 4096;
  constexpr int NS = K / 32;   // K-slabs

  // ring: 4 slots x 32KB; per slot: 16 A units (1KB), then 16 B units.
  __shared__ short lds[65536];

  const int tid = threadIdx.x;

  // T1: bijective XCD swizzle (gridDim.x = 1024, divisible by 8)
  const int bid = blockIdx.x;
  const int id  = (bid & 7) * (gridDim.x >> 3) + (bid >> 3);

  int m0, n0, z = 0;
  size_t aoff = 0, boff = 0;
  if constexpr (MODE == 3 || MODE == 4) {
    z  = id >> 6;                       // 16 batches
    m0 = ((id >> 3) & 7) << 8;          // 8 m-tiles
    n0 = (id & 7) << 8;                 // 8 n-tiles
    aoff = boff = (size_t)z << 22;
  } else {
    m0 = (id >> 4) << 8;                // 64 m-tiles
    n0 = (id & 15) << 8;                // 16 n-tiles (n fastest: A-panel reuse)
  }

  const int l = tid & 63;
  const int w = tid >> 6;               // wave id 0..3

  // ---- staging (frag-major): A unit u = rows [16u,16u+16) x k32; lane l
  //      holds (row 16u+(l&15), k (l>>4)*8..+7) = 16B at unit_base + l*16B.
  //      Wave w stages A units {4w..4w+3} and B units {4w..4w+3} per slab.
  const int srow = l & 15;
  const int skol = (l >> 4) * 8;
  const short* ApS = Ag + aoff + (size_t)(m0 + 64 * w + srow) * K + skol;
  const short* BpS = Bg + boff + (size_t)(n0 + 64 * w + srow) * K + skol;
  short* laS = &lds[(4 * w) * 512 + l * 8];
  short* lbS = &lds[8192 + (4 * w) * 512 + l * 8];

  auto STAGE = [&](int t) {
    const int s = (t & 3) << 14;
    const size_t k = (size_t)t * 32;
#pragma unroll
    for (int j = 0; j < 4; ++j) {
      gld_lds16(ApS + (size_t)j * 16 * K + k, laS + j * 512 + s);
      gld_lds16(BpS + (size_t)j * 16 * K + k, lbS + j * 512 + s);
    }
  };

  // ---- fragment read bases: wave w owns m rows [ (w>>1)*128 .. +128 ),
  //      n cols [ (w&1)*128 .. +128 ) -> A units 8*(w>>1)+i, B units 8*(w&1)+j
  const int aU = (w >> 1) * 8;
  const int bU = (w & 1) * 8;
  const int l8 = l * 8;

  f32x4 acc[8][8] = {};

  STAGE(0); STAGE(1); STAGE(2);

  for (int p = 0; p < NS; ++p) {
    if (p + 2 < NS)      asm volatile("s_waitcnt vmcnt(16)" ::: "memory");
    else if (p + 1 < NS) asm volatile("s_waitcnt vmcnt(8)" ::: "memory");
    else                 asm volatile("s_waitcnt vmcnt(0)" ::: "memory");
    __builtin_amdgcn_s_barrier();        // slab p visible to all waves

    if (p + 3 < NS) STAGE(p + 3);        // slot (p-1)&3: WAR-safe (header)

    const int slot = (p & 3) << 14;
    short8_t A[8], B[8];
#pragma unroll
    for (int i = 0; i < 8; ++i)
      A[i] = *(const short8_t*)&lds[slot + (aU + i) * 512 + l8];
#pragma unroll
    for (int j = 0; j < 8; ++j)
      B[j] = *(const short8_t*)&lds[slot + 8192 + (bU + j) * 512 + l8];

    __builtin_amdgcn_s_setprio(1);
#pragma unroll
    for (int m = 0; m < 8; ++m)
#pragma unroll
      for (int n = 0; n < 8; ++n)
        acc[m][n] = __builtin_amdgcn_mfma_f32_16x16x32_bf16(A[m], B[n], acc[m][n], 0, 0, 0);
    __builtin_amdgcn_s_setprio(0);
  }

  // ---- epilogue (NT stores): C/D frag layout col=lane&15, row=(l>>4)*4+r
  const int fr = l & 15;
  const int kq = l >> 4;
  const int wm = (w >> 1) << 7;
  const int wn = (w & 1) << 7;
#pragma unroll
  for (int m = 0; m < 8; ++m) {
#pragma unroll
    for (int n = 0; n < 8; ++n) {
#pragma unroll
      for (int r = 0; r < 4; ++r) {
        const int gm = m0 + wm + m * 16 + kq * 4 + r;
        const int gn = n0 + wn + n * 16 + fr;
        const float v = acc[m][n][r];
        if constexpr (MODE == 0) {
          short* dst = (short*)Cg;
          const int bh = ((gm >> 11) << 1) + (gn >> 11);
          __builtin_nontemporal_store(f2bf(v),
            &dst[((size_t)bh << 22) + ((size_t)(gm & 2047) << 11) + (gn & 2047)]);
        } else if constexpr (MODE == 2) {
          short* dst = (short*)Cg;
          const int bh = ((gm >> 11) << 1) + (gn >> 11);
          __builtin_nontemporal_store(f2bf(v),
            &dst[((size_t)bh << 22) + ((size_t)(gn & 2047) << 11) + (gm & 2047)]);
        } else if constexpr (MODE == 3) {
          float* dst = (float*)Cg;
          const float sv = v * 0.022097086912079608f + bias[((z & 1) << 11) + gn];
          __builtin_nontemporal_store(sv,
            &dst[((size_t)z << 22) + ((size_t)gm << 11) + gn]);
        } else if constexpr (MODE == 4) {
          short* dst = (short*)Cg;
          const size_t row = ((size_t)(z >> 1) << 11) + gm;
          __builtin_nontemporal_store(f2bf(v),
            &dst[(row << 12) + ((size_t)(z & 1) << 11) + gn]);
        } else {
          float* dst = (float*)Cg;
          __builtin_nontemporal_store(v, &dst[(size_t)gm * 4096 + gn]);
        }
      }
    }
  }
}

// row softmax in place (fp32, 2048 wide) + bf16 copy for the PV GEMM.
__global__ __launch_bounds__(256)
void softmax_rows(float* __restrict__ attn, short* __restrict__ outb) {
  float* row  = attn + ((size_t)blockIdx.x << 11);
  short* rowb = outb + ((size_t)blockIdx.x << 11);
  const int tid = threadIdx.x;

  f32x4 v0 = __builtin_nontemporal_load((const f32x4*)(row + tid * 8));
  f32x4 v1 = __builtin_nontemporal_load((const f32x4*)(row + tid * 8 + 4));

  float m = fmaxf(fmaxf(fmaxf(v0[0], v0[1]), fmaxf(v0[2], v0[3])),
                  fmaxf(fmaxf(v1[0], v1[1]), fmaxf(v1[2], v1[3])));
#pragma unroll
  for (int off = 1; off < 64; off <<= 1) m = fmaxf(m, __shfl_xor(m, off));

  __shared__ float redm[4];
  __shared__ float reds[4];
  if ((tid & 63) == 0) redm[tid >> 6] = m;
  __syncthreads();
  m = fmaxf(fmaxf(redm[0], redm[1]), fmaxf(redm[2], redm[3]));

  float e[8];
#pragma unroll
  for (int i = 0; i < 4; ++i) e[i]     = expf(v0[i] - m);
#pragma unroll
  for (int i = 0; i < 4; ++i) e[4 + i] = expf(v1[i] - m);
  float s = 0.f;
#pragma unroll
  for (int i = 0; i < 8; ++i) s += e[i];
#pragma unroll
  for (int off = 1; off < 64; off <<= 1) s += __shfl_xor(s, off);
  if ((tid & 63) == 0) reds[tid >> 6] = s;
  __syncthreads();
  s = reds[0] + reds[1] + reds[2] + reds[3];

  const float inv = 1.0f / s;
  f32x4 o0, o1;
#pragma unroll
  for (int i = 0; i < 4; ++i) { o0[i] = e[i] * inv; o1[i] = e[4 + i] * inv; }
  __builtin_nontemporal_store(o0, (f32x4*)(row + tid * 8));
  __builtin_nontemporal_store(o1, (f32x4*)(row + tid * 8 + 4));
  *(short8_t*)(rowb + tid * 8) = cvt8(o0, o1);
}

extern "C" void kernel_launch(void* const* d_in, const int* in_sizes, int n_in,
                              void* d_out, int out_size, void* d_ws, size_t ws_size,
                              hipStream_t stream) {
  const float* x  = (const float*)d_in[0];
  const float* Wq = (const float*)d_in[1];
  const float* Wk = (const float*)d_in[2];
  const float* Wv = (const float*)d_in[3];
  const float* Wo = (const float*)d_in[4];
  const float* pb = (const float*)d_in[5];

  float* y_out = (float*)d_out;                       // 8*2048*4096 f32
  float* attn  = y_out + (size_t)8 * 2048 * 4096;     // 16*2048*2048 f32

  const size_t NEED = 4ull * 67108864ull * 2ull;      // 512 MB
  if (ws_size < NEED) return;
  short* buf0 = (short*)d_ws;
  short* buf1 = buf0 + 67108864;
  short* buf2 = buf1 + 67108864;
  short* buf3 = buf2 + 67108864;

  short* xb      = buf0;             // x bf16 (16384 x 4096)
  short* qb      = buf1;             // (b,h,t,d)
  short* kb      = buf2;             // (b,h,t,d)
  short* vtb     = buf3;             // (b,h,d,s)
  short* wob     = buf0;             // Wo bf16 (reuses xb after projections)
  short* attn_bf = buf1;             // bf16 probs (reuses qb after scores)
  short* yb      = buf2;             // attn@v bf16 (reuses kb after scores)
  short* wb      = (short*)attn;     // W staging in d_out attn region
                                     // (dead until scores GEMM writes it)

  const dim3 blk(256);
  const dim3 gcv(2048);
  const dim3 g1k(1024);

  cvt_f32_bf16<<<gcv, blk, 0, stream>>>(x, xb, 67108864 / 8);

  cvt_f32_bf16<<<gcv, blk, 0, stream>>>(Wq, wb, 16777216 / 8);
  gemm256<0><<<g1k, blk, 0, stream>>>(xb, wb, qb, nullptr);
  cvt_f32_bf16<<<gcv, blk, 0, stream>>>(Wk, wb, 16777216 / 8);
  gemm256<0><<<g1k, blk, 0, stream>>>(xb, wb, kb, nullptr);
  cvt_f32_bf16<<<gcv, blk, 0, stream>>>(Wv, wb, 16777216 / 8);
  gemm256<2><<<g1k, blk, 0, stream>>>(xb, wb, vtb, nullptr);

  cvt_f32_bf16<<<gcv, blk, 0, stream>>>(Wo, wob, 16777216 / 8);  // x dead now

  gemm256<3><<<g1k, blk, 0, stream>>>(qb, kb, attn, pb);
  softmax_rows<<<dim3(32768), blk, 0, stream>>>(attn, attn_bf);
  gemm256<4><<<g1k, blk, 0, stream>>>(attn_bf, vtb, yb, nullptr);
  gemm256<5><<<g1k, blk, 0, stream>>>(yb, wob, y_out, nullptr);
}